// Round 1
// baseline (1391.551 us; speedup 1.0000x reference)
//
#include <hip/hip_runtime.h>
#include <math.h>

#define BB 12
#define C1 64
#define H1 128
#define W1 352
#define HW1 (H1*W1)          /* 45056 */
#define C5 512
#define H5 64
#define W5 176
#define N5 (H5*W5)           /* 11264 */
#define BEVH 128
#define BEVW 128
#define BEVHW (BEVH*BEVW)    /* 16384 */
#define DCH 48

/* ws float offsets */
#define OFF_W1T   0            /* [c64][o64]   folded red1_g   */
#define OFF_WST   4096         /* [c64][s32]   folded skip_g   */
#define OFF_W5T   6144         /* [c512][o64]  folded red5_g   */
#define OFF_WDT   38912        /* [c512][d48]  folded dep5_g   */
#define OFF_WMT   63488        /* [tap9][c64][o128] folded main_g */
#define OFF_BINS  137216       /* [48] */
#define OFF_KINV  137264       /* [b12][9] */

#define OUT_SZ ((size_t)BB*128*BEVHW)   /* 25165824 */

__global__ void prep_kernel(const float* __restrict__ r1w, const float* __restrict__ r1g,
                            const float* __restrict__ skw, const float* __restrict__ skg,
                            const float* __restrict__ r5w, const float* __restrict__ r5g,
                            const float* __restrict__ dpw, const float* __restrict__ dpg,
                            const float* __restrict__ mw,  const float* __restrict__ mg,
                            const float* __restrict__ intr, float* __restrict__ ws)
{
    int t = blockIdx.x*blockDim.x + threadIdx.x;
    int stride = gridDim.x*blockDim.x;
    for (int i=t; i<64*64; i+=stride){ int c=i>>6, o=i&63;  ws[OFF_W1T + c*64+o] = r1w[o*64+c]*r1g[o]; }
    for (int i=t; i<64*32; i+=stride){ int c=i>>5, s=i&31;  ws[OFF_WST + c*32+s] = skw[s*64+c]*skg[s]; }
    for (int i=t; i<512*64; i+=stride){ int c=i>>6, o=i&63; ws[OFF_W5T + c*64+o] = r5w[o*512+c]*r5g[o]; }
    for (int i=t; i<512*48; i+=stride){ int c=i/48, d=i-c*48; ws[OFF_WDT + c*48+d] = dpw[d*512+c]*dpg[d]; }
    for (int i=t; i<9*64*128; i+=stride){
        int o=i&127; int rest=i>>7; int c=rest&63; int tap=rest>>6; int dy=tap/3, dx=tap-dy*3;
        ws[OFF_WMT + i] = mw[((o*64+c)*3+dy)*3+dx]*mg[o];
    }
    for (int i=t; i<DCH; i+=stride){ ws[OFF_BINS+i] = expf(logf(60.0f)*(float)i/47.0f); }
    for (int i=t; i<BB; i+=stride){
        const float* K = intr + i*9;
        float a=K[0],b=K[1],c=K[2],d=K[3],e=K[4],f=K[5],g=K[6],h=K[7],k=K[8];
        float det = a*(e*k-f*h) - b*(d*k-f*g) + c*(d*h-e*g);
        float id = 1.0f/det;
        float* o_ = ws + OFF_KINV + i*9;
        o_[0]=(e*k-f*h)*id; o_[1]=(c*h-b*k)*id; o_[2]=(b*f-c*e)*id;
        o_[3]=(f*g-d*k)*id; o_[4]=(a*k-c*g)*id; o_[5]=(c*d-a*f)*id;
        o_[6]=(d*h-e*g)*id; o_[7]=(b*g-a*h)*id; o_[8]=(a*e-b*d)*id;
    }
}

/* stage1 -> r1 -> skip (fused, per-pixel) */
__global__ __launch_bounds__(256) void kA(const float* __restrict__ s1, const float* __restrict__ ws,
                                          const float* __restrict__ b1, const float* __restrict__ bsk,
                                          float* __restrict__ outskip)
{
    int p = blockIdx.x*256 + threadIdx.x;
    if (p >= BB*HW1) return;
    int b = p / HW1; int hw = p - b*HW1;
    const float* x  = s1 + (size_t)b*C1*HW1 + hw;
    const float* w1 = ws + OFF_W1T;
    float y[64];
    #pragma unroll
    for (int o=0;o<64;o++) y[o]=0.f;
    #pragma unroll 2
    for (int c=0;c<64;c++){
        float v = x[(size_t)c*HW1];
        const float* wr = w1 + c*64;
        #pragma unroll
        for (int o=0;o<64;o++) y[o] += v*wr[o];
    }
    #pragma unroll
    for (int o=0;o<64;o++) y[o] = fmaxf(y[o]+b1[o], 0.f);
    float s[32];
    #pragma unroll
    for (int i=0;i<32;i++) s[i]=0.f;
    const float* w2 = ws + OFF_WST;
    #pragma unroll 2
    for (int o=0;o<64;o++){
        float v = y[o];
        const float* wr = w2 + o*32;
        #pragma unroll
        for (int i=0;i<32;i++) s[i] += v*wr[i];
    }
    float* op = outskip + (size_t)b*32*HW1 + hw;
    #pragma unroll
    for (int i=0;i<32;i++) op[(size_t)i*HW1] = fmaxf(s[i]+bsk[i], 0.f);
}

/* stage5 -> reduced + depth softmax + geometry + BEV scatter */
__global__ __launch_bounds__(256) void kB(const float* __restrict__ s5, const float* __restrict__ ws,
                                          const float* __restrict__ b5, const float* __restrict__ bd,
                                          const float* __restrict__ extr, float* __restrict__ bev)
{
    int p = blockIdx.x*256 + threadIdx.x;
    if (p >= BB*N5) return;
    int b = p / N5; int n = p - b*N5;
    const float* x  = s5 + (size_t)b*C5*N5 + n;
    const float* w5 = ws + OFF_W5T;
    const float* wd = ws + OFF_WDT;
    float aR[64], aD[48];
    #pragma unroll
    for (int o=0;o<64;o++) aR[o]=0.f;
    #pragma unroll
    for (int d=0;d<48;d++) aD[d]=0.f;
    #pragma unroll 2
    for (int c=0;c<512;c++){
        float v = x[(size_t)c*N5];
        const float* wr = w5 + c*64;
        const float* wq = wd + c*48;
        #pragma unroll
        for (int o=0;o<64;o++) aR[o] += v*wr[o];
        #pragma unroll
        for (int d=0;d<48;d++) aD[d] += v*wq[d];
    }
    #pragma unroll
    for (int o=0;o<64;o++) aR[o] = fmaxf(aR[o]+b5[o], 0.f);
    float m = -1e30f;
    #pragma unroll
    for (int d=0;d<48;d++){ aD[d] = (aD[d]+bd[d])*10.f; m = fmaxf(m, aD[d]); }
    float sum=0.f, dsum=0.f;
    const float* bins = ws + OFF_BINS;
    #pragma unroll
    for (int d=0;d<48;d++){ float e = expf(aD[d]-m); sum += e; dsum += e*bins[d]; }
    float depth = dsum/sum;
    depth = fminf(fmaxf(depth, 1.0f), 65.0f);

    float px = (float)(n - (n/W5)*W5);
    float py = (float)(n / W5);
    const float* Ki = ws + OFF_KINV + b*9;
    float cx = depth*(Ki[0]*px + Ki[1]*py + Ki[2]);
    float cy = depth*(Ki[3]*px + Ki[4]*py + Ki[5]);
    float cz = depth*(Ki[6]*px + Ki[7]*py + Ki[8]);
    const float* E = extr + b*16;
    float ex = E[0]*cx + E[1]*cy + E[2]*cz  + E[3];
    float ey = E[4]*cx + E[5]*cy + E[6]*cz  + E[7];
    float ez = E[8]*cx + E[9]*cy + E[10]*cz + E[11];
    bool valid = (ex >= -51.2f) && (ex < 51.2f) && (ey >= -51.2f) && (ey < 51.2f)
              && (ez >= -5.0f)  && (ez < 3.0f);
    int bx = (int)floorf(ex/0.4f + 64.0f);
    int by = (int)floorf(ey/0.4f + 64.0f);
    valid = valid && (bx>=0) && (bx<BEVW) && (by>=0) && (by<BEVH);
    if (valid){
        float wgt = expf(-0.05f*fabsf(ez));
        float* bp = bev + (size_t)b*64*BEVHW + (size_t)by*BEVW + bx;
        #pragma unroll
        for (int o=0;o<64;o++) atomicAdd(bp + (size_t)o*BEVHW, aR[o]*wgt);
    }
}

/* 3x3 conv over BEV (NCHW) + bn + relu; thread = pixel, 64 out-channel accs */
__global__ __launch_bounds__(128) void kC(const float* __restrict__ bev, const float* __restrict__ ws,
                                          const float* __restrict__ bm, float* __restrict__ out)
{
    int x = threadIdx.x;
    int y = blockIdx.x;
    int bz = blockIdx.y;
    int b = bz >> 1; int obase = (bz & 1) * 64;
    const float* bp = bev + (size_t)b*64*BEVHW;
    float acc[64];
    #pragma unroll
    for (int o=0;o<64;o++) acc[o]=0.f;
    for (int dy=0; dy<3; dy++){
        int yy = y + dy - 1;
        if (yy < 0 || yy >= BEVH) continue;
        for (int dx=0; dx<3; dx++){
            int xx = x + dx - 1;
            bool ok = (xx >= 0) && (xx < BEVW);
            int xc = min(max(xx,0), BEVW-1);
            const float* wt = ws + OFF_WMT + (size_t)((dy*3+dx)*64)*128 + obase;
            const float* ip = bp + (size_t)yy*BEVW + xc;
            #pragma unroll 2
            for (int c=0;c<64;c++){
                float v = ip[(size_t)c*BEVHW];
                v = ok ? v : 0.f;
                const float* wr = wt + c*128;
                #pragma unroll
                for (int o=0;o<64;o++) acc[o] += v*wr[o];
            }
        }
    }
    float* op = out + (size_t)b*128*BEVHW + (size_t)obase*BEVHW + (size_t)y*BEVW + x;
    #pragma unroll
    for (int o=0;o<64;o++) op[(size_t)o*BEVHW] = fmaxf(acc[o] + bm[obase+o], 0.f);
}

extern "C" void kernel_launch(void* const* d_in, const int* in_sizes, int n_in,
                              void* d_out, int out_size, void* d_ws, size_t ws_size,
                              hipStream_t stream)
{
    const float* stage1 = (const float*)d_in[0];
    const float* stage5 = (const float*)d_in[1];
    const float* intr   = (const float*)d_in[2];
    const float* extr   = (const float*)d_in[3];
    const float* r1w=(const float*)d_in[4];  const float* r1g=(const float*)d_in[5];  const float* r1b=(const float*)d_in[6];
    const float* skw=(const float*)d_in[7];  const float* skg=(const float*)d_in[8];  const float* skb=(const float*)d_in[9];
    const float* r5w=(const float*)d_in[10]; const float* r5g=(const float*)d_in[11]; const float* r5b=(const float*)d_in[12];
    const float* dpw=(const float*)d_in[13]; const float* dpg=(const float*)d_in[14]; const float* dpb=(const float*)d_in[15];
    const float* mw =(const float*)d_in[16]; const float* mg =(const float*)d_in[17]; const float* mb =(const float*)d_in[18];

    float* out  = (float*)d_out;
    float* skip = out + OUT_SZ;
    float* ws   = (float*)d_ws;
    /* bev scratch lives in the skip region of d_out (12.58M floats < 17.3M);
       skip itself is written LAST (kA), after kC has consumed bev. */
    float* bev  = skip;

    prep_kernel<<<dim3(544), dim3(256), 0, stream>>>(r1w,r1g,skw,skg,r5w,r5g,dpw,dpg,mw,mg,intr,ws);
    hipMemsetAsync(bev, 0, (size_t)BB*64*BEVHW*sizeof(float), stream);
    kB<<<dim3((BB*N5+255)/256), dim3(256), 0, stream>>>(stage5, ws, r5b, dpb, extr, bev);
    kC<<<dim3(128, BB*2), dim3(128), 0, stream>>>(bev, ws, mb, out);
    kA<<<dim3((BB*HW1+255)/256), dim3(256), 0, stream>>>(stage1, ws, r1b, skb, skip);
}